// Round 2
// baseline (461.211 us; speedup 1.0000x reference)
//
#include <hip/hip_runtime.h>
#include <hip/hip_bf16.h>

// DMoN pooling, MI355X. B=8, N=4096, C=128, K=64.
//  k_assign : s = softmax(x@W+b) via fp16-split MFMA; writes s (f32) + packed
//             S fragments (fp16 hi+lo) in MFMA B-layout.
//  k_big    : Y = adj @ S, barrier-free main loop: adj 2-iter register
//             prefetch (HBM, read exactly once), S fragments read directly
//             from global (L2-resident, 1 MB/batch); deg rowsum for free;
//             epilogue folds oadj_part = S_tile^T @ Y_tile.
//  k_small / k_reduce / k_finalize / k_scalars: partials, losses, normalize.
// All reductions deterministic (fixed-order partials, no FP atomics).

typedef _Float16 f16x8 __attribute__((ext_vector_type(8)));
typedef float f32x4 __attribute__((ext_vector_type(4)));

#define MFMA16(a, b, c) __builtin_amdgcn_mfma_f32_16x16x32_f16((a), (b), (c), 0, 0, 0)

__device__ __forceinline__ void gld_lds16(const void* g, void* l) {
  __builtin_amdgcn_global_load_lds(
      (const __attribute__((address_space(1))) void*)g,
      (__attribute__((address_space(3))) void*)l, 16, 0, 0);
}

template <int NCHUNK>
__device__ __forceinline__ void stage_lds(const void* g, void* lbase, int tid) {
  char* ld = (char*)lbase + (tid >> 6) * 1024;   // wave-uniform base; HW adds lane*16
  const char* gs = (const char*)g + tid * 16;
#pragma unroll
  for (int p = 0; p < NCHUNK; ++p)
    gld_lds16(gs + p * 4096, ld + p * 4096);
}

// ---------------------------------------------------------------- k_assign
__global__ __launch_bounds__(256) void k_assign(
    const float* __restrict__ x, const float* __restrict__ w,
    const float* __restrict__ bias, float* __restrict__ s_out,
    _Float16* __restrict__ sB) {
  __shared__ __align__(16) _Float16 wT[2][64][136];
  __shared__ __align__(16) float sT[64][76];
  const int b = blockIdx.x & 7;
  const int it = blockIdx.x >> 3;
  const int n_base = it * 64;
  const int tid = threadIdx.x;

  for (int idx = tid; idx < 8192; idx += 256) {
    int c = idx >> 6, k = idx & 63;
    float v = w[idx];
    _Float16 h = (_Float16)v;
    wT[0][k][c] = h;
    wT[1][k][c] = (_Float16)(v - (float)h);
  }
  const int l = tid & 63, wv = tid >> 6;
  const int l15 = l & 15, g = l >> 4;
  float bv[4];
#pragma unroll
  for (int ct = 0; ct < 4; ++ct) bv[ct] = bias[ct * 16 + l15];
  __syncthreads();

  f32x4 acc[4];
#pragma unroll
  for (int ct = 0; ct < 4; ++ct) acc[ct] = (f32x4){bv[ct], bv[ct], bv[ct], bv[ct]};

  const float* xrow = x + ((size_t)(b * 4096 + n_base + wv * 16 + l15)) * 128;
#pragma unroll
  for (int cs = 0; cs < 4; ++cs) {
    const int c0 = cs * 32;
    f32x4 r0 = *(const f32x4*)(xrow + c0 + 8 * g);
    f32x4 r1 = *(const f32x4*)(xrow + c0 + 8 * g + 4);
    f16x8 ah, al;
#pragma unroll
    for (int j = 0; j < 4; ++j) {
      float v0 = r0[j]; _Float16 h0 = (_Float16)v0;
      ah[j] = h0; al[j] = (_Float16)(v0 - (float)h0);
      float v1 = r1[j]; _Float16 h1 = (_Float16)v1;
      ah[4 + j] = h1; al[4 + j] = (_Float16)(v1 - (float)h1);
    }
#pragma unroll
    for (int ct = 0; ct < 4; ++ct) {
      f16x8 bh = *(const f16x8*)&wT[0][ct * 16 + l15][c0 + 8 * g];
      f16x8 bl = *(const f16x8*)&wT[1][ct * 16 + l15][c0 + 8 * g];
      acc[ct] = MFMA16(ah, bh, acc[ct]);
      acc[ct] = MFMA16(al, bh, acc[ct]);
      acc[ct] = MFMA16(ah, bl, acc[ct]);
    }
  }

#pragma unroll
  for (int r = 0; r < 4; ++r) {
    float m = fmaxf(fmaxf(acc[0][r], acc[1][r]), fmaxf(acc[2][r], acc[3][r]));
#pragma unroll
    for (int off = 1; off < 16; off <<= 1) m = fmaxf(m, __shfl_xor(m, off, 64));
    float e[4], sum = 0.f;
#pragma unroll
    for (int ct = 0; ct < 4; ++ct) { e[ct] = __expf(acc[ct][r] - m); sum += e[ct]; }
#pragma unroll
    for (int off = 1; off < 16; off <<= 1) sum += __shfl_xor(sum, off, 64);
    float inv = 1.0f / sum;
#pragma unroll
    for (int ct = 0; ct < 4; ++ct) acc[ct][r] = e[ct] * inv;
  }

  const int row_l = wv * 16 + 4 * g;
  float* srow = s_out + ((size_t)(b * 4096 + n_base)) * 64;
#pragma unroll
  for (int r = 0; r < 4; ++r)
#pragma unroll
    for (int ct = 0; ct < 4; ++ct) {
      srow[(size_t)(row_l + r) * 64 + ct * 16 + l15] = acc[ct][r];
      sT[ct * 16 + l15][row_l + r] = acc[ct][r];
    }
  __syncthreads();

  // repack to B-fragment layout: [hl][ks][ct][lane][8] fp16
  _Float16* dst = sB + (size_t)(b * 64 + it) * 8192;
#pragma unroll
  for (int p = 0; p < 4; ++p) {
    int slot = tid + 256 * p;
    int hl = slot >> 9, ks = (slot >> 8) & 1, ct = (slot >> 6) & 3, ln = slot & 63;
    int col = ct * 16 + (ln & 15);
    int row0 = ks * 32 + 8 * (ln >> 4);
    f16x8 o;
#pragma unroll
    for (int j = 0; j < 8; ++j) {
      float v = sT[col][row0 + j];
      _Float16 h = (_Float16)v;
      o[j] = hl ? (_Float16)(v - (float)h) : h;
    }
    *(f16x8*)(dst + slot * 8) = o;
  }
}

// ---------------------------------------------------------------- k_big
// grid 512 (b = blockIdx&7 -> XCD pin, nt = blockIdx>>3), block 256.
// Barrier-free main loop; adj 2-iter register prefetch; B-frags direct from L2.
__global__ __launch_bounds__(256) void k_big(
    const float* __restrict__ adj, const _Float16* __restrict__ sB,
    const float* __restrict__ s_out, float* __restrict__ deg,
    float* __restrict__ oadj_part) {
  __shared__ __align__(16) float sl[4096];
  __shared__ __align__(16) float Yl[4096];
  const int b = blockIdx.x & 7;
  const int nt = blockIdx.x >> 3;
  const int n_base = nt * 64;
  const int tid = threadIdx.x;
  const int l = tid & 63, wv = tid >> 6;
  const int l15 = l & 15, g = l >> 4;

  stage_lds<4>(s_out + ((size_t)(b * 4096 + n_base)) * 64, sl, tid);

  const f16x8* fbase = (const f16x8*)(sB + (size_t)b * 64 * 8192) + l;
  const float* arow =
      adj + ((size_t)b * 4096 + n_base + wv * 16 + l15) * 4096 + 8 * g;

  f32x4 A0, A1, A2, A3, B0, B1, B2, B3;
  A0 = *(const f32x4*)(arow);        A1 = *(const f32x4*)(arow + 4);
  A2 = *(const f32x4*)(arow + 32);   A3 = *(const f32x4*)(arow + 36);
  B0 = *(const f32x4*)(arow + 64);   B1 = *(const f32x4*)(arow + 68);
  B2 = *(const f32x4*)(arow + 96);   B3 = *(const f32x4*)(arow + 100);

  f32x4 acc[4] = {};
  float dacc = 0.f;

  // one phase: frag-loads(itv) issued FIRST, adj prefetch(itv+2) second, so
  // the MFMA's frag wait (in-order vmcnt) leaves the adj prefetch in flight.
  auto phase = [&](f32x4& C0, f32x4& C1, f32x4& C2, f32x4& C3, int itv) {
    const f16x8* fb = fbase + (size_t)itv * 1024;
    f16x8 Fh[8];
#pragma unroll
    for (int q = 0; q < 8; ++q) Fh[q] = fb[q * 64];
    f16x8 a0, a1;
#pragma unroll
    for (int j = 0; j < 4; ++j) {
      a0[j] = (_Float16)C0[j]; a0[4 + j] = (_Float16)C1[j];
      a1[j] = (_Float16)C2[j]; a1[4 + j] = (_Float16)C3[j];
    }
    dacc += C0[0] + C0[1] + C0[2] + C0[3] + C1[0] + C1[1] + C1[2] + C1[3] +
            C2[0] + C2[1] + C2[2] + C2[3] + C3[0] + C3[1] + C3[2] + C3[3];
    if (itv + 2 < 64) {  // reload this buffer with iter itv+2
      const float* an = arow + (itv + 2) * 64;
      C0 = *(const f32x4*)(an);       C1 = *(const f32x4*)(an + 4);
      C2 = *(const f32x4*)(an + 32);  C3 = *(const f32x4*)(an + 36);
    }
    f16x8 Fl[8];
#pragma unroll
    for (int q = 0; q < 8; ++q) Fl[q] = fb[(8 + q) * 64];
#pragma unroll
    for (int ct = 0; ct < 4; ++ct) {
      acc[ct] = MFMA16(a0, Fh[ct], acc[ct]);
      acc[ct] = MFMA16(a1, Fh[4 + ct], acc[ct]);
    }
#pragma unroll
    for (int ct = 0; ct < 4; ++ct) {
      acc[ct] = MFMA16(a0, Fl[ct], acc[ct]);
      acc[ct] = MFMA16(a1, Fl[4 + ct], acc[ct]);
    }
  };

#pragma unroll 2
  for (int it = 0; it < 64; it += 2) {
    phase(A0, A1, A2, A3, it);
    phase(B0, B1, B2, B3, it + 1);
  }

  // deg (rowsum of adj), deterministic
  dacc += __shfl_xor(dacc, 16, 64);
  dacc += __shfl_xor(dacc, 32, 64);
  if (l < 16) deg[b * 4096 + n_base + wv * 16 + l] = dacc;

  // Y tile -> LDS
#pragma unroll
  for (int r = 0; r < 4; ++r)
#pragma unroll
    for (int ct = 0; ct < 4; ++ct)
      Yl[(wv * 16 + 4 * g + r) * 64 + ct * 16 + l15] = acc[ct][r];
  __syncthreads();

  // fold: oadj_part[b][nt] = S_tile^T @ Y_tile  (f32)
  const int kq = tid >> 4, lq = tid & 15;
  f32x4 a2[4] = {};
  for (int r = 0; r < 64; ++r) {
    f32x4 s4 = *(const f32x4*)(sl + r * 64 + kq * 4);
    f32x4 y4 = *(const f32x4*)(Yl + r * 64 + lq * 4);
#pragma unroll
    for (int i = 0; i < 4; ++i)
#pragma unroll
      for (int j = 0; j < 4; ++j) a2[i][j] += s4[i] * y4[j];
  }
  float* op = oadj_part + ((size_t)(b * 64 + nt)) * 4096;
#pragma unroll
  for (int i = 0; i < 4; ++i)
    *(f32x4*)(op + (kq * 4 + i) * 64 + lq * 4) = a2[i];
}

// ---------------------------------------------------------------- k_small
__global__ __launch_bounds__(256) void k_small(
    const float* __restrict__ s_out, const float* __restrict__ x,
    float* __restrict__ ss_part, float* __restrict__ p_part) {
  __shared__ __align__(16) float sc[32 * 64];
  __shared__ __align__(16) float xc[32 * 128];
  const int b = blockIdx.x & 7;
  const int ch = blockIdx.x >> 3;
  const int tid = threadIdx.x;
  const int kq = tid >> 4, cq = tid & 15;
  f32x4 ssa[4] = {};
  f32x4 pa[8] = {};
  for (int sub = 0; sub < 4; ++sub) {
    if (sub) __syncthreads();
    const int nb = ch * 128 + sub * 32;
    stage_lds<2>(s_out + ((size_t)(b * 4096 + nb)) * 64, sc, tid);
    stage_lds<4>(x + ((size_t)(b * 4096 + nb)) * 128, xc, tid);
    __syncthreads();
    for (int n = 0; n < 32; ++n) {
      f32x4 s4 = *(const f32x4*)(sc + n * 64 + kq * 4);
      f32x4 s4b = *(const f32x4*)(sc + n * 64 + cq * 4);
      f32x4 x4a = *(const f32x4*)(xc + n * 128 + cq * 8);
      f32x4 x4b = *(const f32x4*)(xc + n * 128 + cq * 8 + 4);
#pragma unroll
      for (int i = 0; i < 4; ++i) {
#pragma unroll
        for (int j = 0; j < 4; ++j) {
          ssa[i][j] += s4[i] * s4b[j];
          pa[i * 2][j] += s4[i] * x4a[j];
          pa[i * 2 + 1][j] += s4[i] * x4b[j];
        }
      }
    }
  }
  float* sp = ss_part + ((size_t)(b * 32 + ch)) * 4096;
  float* pp = p_part + ((size_t)(b * 32 + ch)) * 8192;
#pragma unroll
  for (int i = 0; i < 4; ++i) {
    *(f32x4*)(sp + (kq * 4 + i) * 64 + cq * 4) = ssa[i];
    *(f32x4*)(pp + (kq * 4 + i) * 128 + cq * 8) = pa[i * 2];
    *(f32x4*)(pp + (kq * 4 + i) * 128 + cq * 8 + 4) = pa[i * 2 + 1];
  }
}

// ---------------------------------------------------------------- k_reduce
__global__ __launch_bounds__(256) void k_reduce(
    const float* __restrict__ oadj_part, const float* __restrict__ ss_part,
    const float* __restrict__ p_part, float* __restrict__ oadj_raw,
    float* __restrict__ ss_sum, float* __restrict__ out_feat) {
  const int gid = blockIdx.x * 256 + threadIdx.x;
  if (gid < 32768) {
    int b = gid >> 12, e = gid & 4095;
    float s = 0.f;
    for (int t = 0; t < 64; ++t) s += oadj_part[((size_t)(b * 64 + t)) * 4096 + e];
    oadj_raw[gid] = s;
  } else if (gid < 65536) {
    int g2 = gid - 32768, b = g2 >> 12, e = g2 & 4095;
    float s = 0.f;
    for (int t = 0; t < 32; ++t) s += ss_part[((size_t)(b * 32 + t)) * 4096 + e];
    ss_sum[g2] = s;
  } else {
    int g3 = gid - 65536, b = g3 >> 13, e = g3 & 8191;
    float s = 0.f;
    for (int t = 0; t < 32; ++t) s += p_part[((size_t)(b * 32 + t)) * 8192 + e];
    const float scale = 1.0507009873554805f, alpha = 1.6732632423543772f;
    out_feat[g3] = s > 0.f ? scale * s : scale * alpha * (expf(s) - 1.f);
  }
}

// ---------------------------------------------------------------- k_finalize
__global__ __launch_bounds__(256) void k_finalize(
    const float* __restrict__ oadj_raw, const float* __restrict__ ss_sum,
    const float* __restrict__ deg, const float* __restrict__ s_out,
    float* __restrict__ out_adj, float* __restrict__ loss_part) {
  __shared__ float red[256];
  __shared__ float q1[4][64], q2[4][64];
  __shared__ float ca[64], dvec[64];
  __shared__ float sh_scalar;
  const int b = blockIdx.x, t = threadIdx.x;
  const float* degb = deg + b * 4096;
  const float* ob = oadj_raw + b * 4096;
  const float* ssb = ss_sum + b * 4096;

  float p = 0.f;
  for (int i = t; i < 4096; i += 256) p += degb[i];
  red[t] = p; __syncthreads();
  for (int o = 128; o > 0; o >>= 1) { if (t < o) red[t] += red[t + o]; __syncthreads(); }
  if (t == 0) sh_scalar = red[0];
  __syncthreads();
  const float sm = sh_scalar;
  __syncthreads();

  const int k = t & 63, q = t >> 6;
  const float* sb = s_out + (size_t)b * 4096 * 64;
  float cs = 0.f, cac = 0.f;
  for (int n = q; n < 4096; n += 4) {
    float sv = sb[(size_t)n * 64 + k];
    cs += sv; cac += sv * degb[n];
  }
  q1[q][k] = cs; q2[q][k] = cac;
  __syncthreads();
  float csize_k = 0.f;
  if (t < 64) {
    csize_k = q1[0][t] + q1[1][t] + q1[2][t] + q1[3][t];
    ca[t] = q2[0][t] + q2[1][t] + q2[2][t] + q2[3][t];
  }
  __syncthreads();

  float tp = 0.f;
  if (t < 64) { float dg = ob[t * 64 + t]; tp = dg - ca[t] * ca[t] / sm; }
  red[t] = tp; __syncthreads();
  for (int o = 128; o > 0; o >>= 1) { if (t < o) red[t] += red[t + o]; __syncthreads(); }
  const float spectral_b = -red[0] / sm;
  __syncthreads();

  float fp = 0.f;
  for (int i = t; i < 4096; i += 256) { float v = ssb[i]; fp += v * v; }
  red[t] = fp; __syncthreads();
  for (int o = 128; o > 0; o >>= 1) { if (t < o) red[t] += red[t + o]; __syncthreads(); }
  const float fro = sqrtf(red[0]);
  __syncthreads();
  float op2 = 0.f;
  for (int i = t; i < 4096; i += 256) {
    float v = ssb[i] / fro - (((i >> 6) == (i & 63)) ? 0.125f : 0.f);
    op2 += v * v;
  }
  red[t] = op2; __syncthreads();
  for (int o = 128; o > 0; o >>= 1) { if (t < o) red[t] += red[t + o]; __syncthreads(); }
  const float ortho_b = sqrtf(red[0]);
  __syncthreads();

  red[t] = (t < 64) ? csize_k * csize_k : 0.f;
  __syncthreads();
  for (int o = 128; o > 0; o >>= 1) { if (t < o) red[t] += red[t + o]; __syncthreads(); }
  const float cluster_b = sqrtf(red[0]) * 8.f / 4096.f - 1.f;
  __syncthreads();

  float rp = 0.f;
  {
    const float* orow = ob + k * 64;
    for (int lc = q * 16; lc < q * 16 + 16; ++lc)
      if (lc != k) rp += orow[lc];
  }
  q1[q][k] = rp; __syncthreads();
  if (t < 64) dvec[t] = sqrtf(q1[0][t] + q1[1][t] + q1[2][t] + q1[3][t]) + 1e-15f;
  __syncthreads();
  for (int i = t; i < 4096; i += 256) {
    int kk = i >> 6, lc = i & 63;
    float v = (kk == lc) ? 0.f : ob[i] / (dvec[kk] * dvec[lc]);
    out_adj[(size_t)b * 4096 + i] = v;
  }
  if (t == 0) {
    loss_part[b * 3 + 0] = spectral_b;
    loss_part[b * 3 + 1] = ortho_b;
    loss_part[b * 3 + 2] = cluster_b;
  }
}

__global__ void k_scalars(const float* __restrict__ lp, float* __restrict__ o3) {
  if (threadIdx.x == 0) {
    float s = 0.f, o = 0.f, c = 0.f;
    for (int b = 0; b < 8; ++b) { s += lp[b * 3]; o += lp[b * 3 + 1]; c += lp[b * 3 + 2]; }
    o3[0] = s * 0.125f; o3[1] = o * 0.125f; o3[2] = c * 0.125f;
  }
}

extern "C" void kernel_launch(void* const* d_in, const int* in_sizes, int n_in,
                              void* d_out, int out_size, void* d_ws, size_t ws_size,
                              hipStream_t stream) {
  const float* x = (const float*)d_in[0];
  const float* adj = (const float*)d_in[1];
  const float* w = (const float*)d_in[2];
  const float* bias = (const float*)d_in[3];
  float* out = (float*)d_out;
  float* s_out = out;                       // [8,4096,64]
  float* out_feat = out + 2097152;          // [8,64,128]
  float* out_adj = out + 2162688;           // [8,64,64]
  float* out_sc = out + 2195456;            // 3 scalars

  char* ws = (char*)d_ws;
  _Float16* sB = (_Float16*)ws;                              // 8 MB
  float* oadj_part = (float*)(ws + (8u << 20));              // 8 MB
  float* ss_part = (float*)(ws + (16u << 20));               // 4 MB
  float* p_part = (float*)(ws + (20u << 20));                // 8 MB
  float* deg = (float*)(ws + (28u << 20));                   // 128 KB
  float* oadj_raw = (float*)(ws + (28u << 20) + (128u << 10));
  float* ss_sum = (float*)(ws + (28u << 20) + (256u << 10));
  float* loss_part = (float*)(ws + (28u << 20) + (384u << 10));

  k_assign<<<dim3(512), dim3(256), 0, stream>>>(x, w, bias, s_out, sB);
  k_big<<<dim3(512), dim3(256), 0, stream>>>(adj, sB, s_out, deg, oadj_part);
  k_small<<<dim3(256), dim3(256), 0, stream>>>(s_out, x, ss_part, p_part);
  k_reduce<<<dim3(512), dim3(256), 0, stream>>>(oadj_part, ss_part, p_part,
                                                oadj_raw, ss_sum, out_feat);
  k_finalize<<<dim3(8), dim3(256), 0, stream>>>(oadj_raw, ss_sum, deg, s_out,
                                                out_adj, loss_part);
  k_scalars<<<dim3(1), dim3(64), 0, stream>>>(loss_part, out_sc);
}

// Round 3
// 364.696 us; speedup vs baseline: 1.2646x; 1.2646x over previous
//
#include <hip/hip_runtime.h>
#include <hip/hip_bf16.h>

// DMoN pooling, MI355X. B=8, N=4096, C=128, K=64.
//  k_assign : s = softmax(x@W+b) via fp16-split MFMA; writes s (f32) + packed
//             S fragments (fp16 hi+lo) in MFMA B-layout.
//  k_big    : (R1 structure — measured at adj-read BW ceiling) per (b, 64-row
//             tile): Y = adj @ S via mfma_f32_16x16x32_f16; adj streamed
//             global->VGPR read exactly once; S-frag tiles double-buffered in
//             LDS via global_load_lds; deg rowsum free; epilogue folds
//             oadj_part = S_tile^T @ Y_tile.
//  k_small / k_reduce / k_finalize / k_scalars: partials, losses, normalize.
// All reductions deterministic (fixed-order partials, no FP atomics).
// NOTE: timed window includes a ~320us 2.1GB harness fill of d_ws (constant,
// uncontrollable); kernel-side budget is ~90us, floor ~85us.

typedef _Float16 f16x8 __attribute__((ext_vector_type(8)));
typedef float f32x4 __attribute__((ext_vector_type(4)));

#define MFMA16(a, b, c) __builtin_amdgcn_mfma_f32_16x16x32_f16((a), (b), (c), 0, 0, 0)

__device__ __forceinline__ void gld_lds16(const void* g, void* l) {
  __builtin_amdgcn_global_load_lds(
      (const __attribute__((address_space(1))) void*)g,
      (__attribute__((address_space(3))) void*)l, 16, 0, 0);
}

template <int NCHUNK>
__device__ __forceinline__ void stage_lds(const void* g, void* lbase, int tid) {
  char* ld = (char*)lbase + (tid >> 6) * 1024;   // wave-uniform base; HW adds lane*16
  const char* gs = (const char*)g + tid * 16;
#pragma unroll
  for (int p = 0; p < NCHUNK; ++p)
    gld_lds16(gs + p * 4096, ld + p * 4096);
}

// ---------------------------------------------------------------- k_assign
__global__ __launch_bounds__(256) void k_assign(
    const float* __restrict__ x, const float* __restrict__ w,
    const float* __restrict__ bias, float* __restrict__ s_out,
    _Float16* __restrict__ sB) {
  __shared__ __align__(16) _Float16 wT[2][64][136];
  __shared__ __align__(16) float sT[64][76];
  const int b = blockIdx.x & 7;
  const int it = blockIdx.x >> 3;
  const int n_base = it * 64;
  const int tid = threadIdx.x;

  for (int idx = tid; idx < 8192; idx += 256) {
    int c = idx >> 6, k = idx & 63;
    float v = w[idx];
    _Float16 h = (_Float16)v;
    wT[0][k][c] = h;
    wT[1][k][c] = (_Float16)(v - (float)h);
  }
  const int l = tid & 63, wv = tid >> 6;
  const int l15 = l & 15, g = l >> 4;
  float bv[4];
#pragma unroll
  for (int ct = 0; ct < 4; ++ct) bv[ct] = bias[ct * 16 + l15];
  __syncthreads();

  f32x4 acc[4];
#pragma unroll
  for (int ct = 0; ct < 4; ++ct) acc[ct] = (f32x4){bv[ct], bv[ct], bv[ct], bv[ct]};

  const float* xrow = x + ((size_t)(b * 4096 + n_base + wv * 16 + l15)) * 128;
#pragma unroll
  for (int cs = 0; cs < 4; ++cs) {
    const int c0 = cs * 32;
    f32x4 r0 = *(const f32x4*)(xrow + c0 + 8 * g);
    f32x4 r1 = *(const f32x4*)(xrow + c0 + 8 * g + 4);
    f16x8 ah, al;
#pragma unroll
    for (int j = 0; j < 4; ++j) {
      float v0 = r0[j]; _Float16 h0 = (_Float16)v0;
      ah[j] = h0; al[j] = (_Float16)(v0 - (float)h0);
      float v1 = r1[j]; _Float16 h1 = (_Float16)v1;
      ah[4 + j] = h1; al[4 + j] = (_Float16)(v1 - (float)h1);
    }
#pragma unroll
    for (int ct = 0; ct < 4; ++ct) {
      f16x8 bh = *(const f16x8*)&wT[0][ct * 16 + l15][c0 + 8 * g];
      f16x8 bl = *(const f16x8*)&wT[1][ct * 16 + l15][c0 + 8 * g];
      acc[ct] = MFMA16(ah, bh, acc[ct]);
      acc[ct] = MFMA16(al, bh, acc[ct]);
      acc[ct] = MFMA16(ah, bl, acc[ct]);
    }
  }

#pragma unroll
  for (int r = 0; r < 4; ++r) {
    float m = fmaxf(fmaxf(acc[0][r], acc[1][r]), fmaxf(acc[2][r], acc[3][r]));
#pragma unroll
    for (int off = 1; off < 16; off <<= 1) m = fmaxf(m, __shfl_xor(m, off, 64));
    float e[4], sum = 0.f;
#pragma unroll
    for (int ct = 0; ct < 4; ++ct) { e[ct] = __expf(acc[ct][r] - m); sum += e[ct]; }
#pragma unroll
    for (int off = 1; off < 16; off <<= 1) sum += __shfl_xor(sum, off, 64);
    float inv = 1.0f / sum;
#pragma unroll
    for (int ct = 0; ct < 4; ++ct) acc[ct][r] = e[ct] * inv;
  }

  const int row_l = wv * 16 + 4 * g;
  float* srow = s_out + ((size_t)(b * 4096 + n_base)) * 64;
#pragma unroll
  for (int r = 0; r < 4; ++r)
#pragma unroll
    for (int ct = 0; ct < 4; ++ct) {
      srow[(size_t)(row_l + r) * 64 + ct * 16 + l15] = acc[ct][r];
      sT[ct * 16 + l15][row_l + r] = acc[ct][r];
    }
  __syncthreads();

  // repack to B-fragment layout: [hl][ks][ct][lane][8] fp16
  _Float16* dst = sB + (size_t)(b * 64 + it) * 8192;
#pragma unroll
  for (int p = 0; p < 4; ++p) {
    int slot = tid + 256 * p;
    int hl = slot >> 9, ks = (slot >> 8) & 1, ct = (slot >> 6) & 3, ln = slot & 63;
    int col = ct * 16 + (ln & 15);
    int row0 = ks * 32 + 8 * (ln >> 4);
    f16x8 o;
#pragma unroll
    for (int j = 0; j < 8; ++j) {
      float v = sT[col][row0 + j];
      _Float16 h = (_Float16)v;
      o[j] = hl ? (_Float16)(v - (float)h) : h;
    }
    *(f16x8*)(dst + slot * 8) = o;
  }
}

// ---------------------------------------------------------------- k_big
// grid 512 (b = blockIdx&7 -> XCD pin, nt = blockIdx>>3), block 256.
// R1 structure: LDS double-buffered S-frags, per-iter adj register prefetch.
__global__ __launch_bounds__(256) void k_big(
    const float* __restrict__ adj, const _Float16* __restrict__ sB,
    const float* __restrict__ s_out, float* __restrict__ deg,
    float* __restrict__ oadj_part) {
  __shared__ __align__(16) char pool[49152];
  float* Yl = (float*)pool;               // aliases sB buf0 (used after loop)
  float* sl = (float*)(pool + 32768);
  const int b = blockIdx.x & 7;
  const int nt = blockIdx.x >> 3;
  const int n_base = nt * 64;
  const int tid = threadIdx.x;
  const int l = tid & 63, wv = tid >> 6;
  const int l15 = l & 15, g = l >> 4;

  const char* sBb = (const char*)(sB + (size_t)b * 64 * 8192);
  const float* arow = adj + ((size_t)b * 4096 + n_base + wv * 16 + l15) * 4096;

  // prologue: stage s tile (f32, for fold) + sB iter0 + first raw adj
  stage_lds<4>(s_out + ((size_t)(b * 4096 + n_base)) * 64, sl, tid);
  stage_lds<4>(sBb, pool, tid);
  f32x4 c0 = *(const f32x4*)(arow + 8 * g);
  f32x4 c1 = *(const f32x4*)(arow + 8 * g + 4);
  f32x4 c2 = *(const f32x4*)(arow + 32 + 8 * g);
  f32x4 c3 = *(const f32x4*)(arow + 32 + 8 * g + 4);
  f32x4 n0 = {}, n1 = {}, n2 = {}, n3 = {};
  __syncthreads();

  f32x4 acc[4] = {};
  float dacc = 0.f;
  for (int itr = 0; itr < 64; ++itr) {
    const int buf = itr & 1;
    if (itr < 63) {
      stage_lds<4>(sBb + (size_t)(itr + 1) * 16384, pool + (buf ^ 1) * 16384, tid);
      const float* an = arow + (itr + 1) * 64 + 8 * g;
      n0 = *(const f32x4*)(an);
      n1 = *(const f32x4*)(an + 4);
      n2 = *(const f32x4*)(an + 32);
      n3 = *(const f32x4*)(an + 36);
    }
    dacc += c0[0] + c0[1] + c0[2] + c0[3] + c1[0] + c1[1] + c1[2] + c1[3] +
            c2[0] + c2[1] + c2[2] + c2[3] + c3[0] + c3[1] + c3[2] + c3[3];
    f16x8 a0, a1;
#pragma unroll
    for (int j = 0; j < 4; ++j) {
      a0[j] = (_Float16)c0[j]; a0[4 + j] = (_Float16)c1[j];
      a1[j] = (_Float16)c2[j]; a1[4 + j] = (_Float16)c3[j];
    }
    const f16x8* fb = (const f16x8*)(pool + buf * 16384);
#pragma unroll
    for (int ct = 0; ct < 4; ++ct) {
      f16x8 bh0 = fb[(0 + ct) * 64 + l];
      f16x8 bh1 = fb[(4 + ct) * 64 + l];
      f16x8 bl0 = fb[(8 + ct) * 64 + l];
      f16x8 bl1 = fb[(12 + ct) * 64 + l];
      acc[ct] = MFMA16(a0, bh0, acc[ct]);
      acc[ct] = MFMA16(a0, bl0, acc[ct]);
      acc[ct] = MFMA16(a1, bh1, acc[ct]);
      acc[ct] = MFMA16(a1, bl1, acc[ct]);
    }
    __syncthreads();  // drains vmcnt; next iter's buf is staged, prev reads done
    c0 = n0; c1 = n1; c2 = n2; c3 = n3;
  }

  // deg (rowsum of adj), deterministic
  dacc += __shfl_xor(dacc, 16, 64);
  dacc += __shfl_xor(dacc, 32, 64);
  if (l < 16) deg[b * 4096 + n_base + wv * 16 + l] = dacc;

  // Y tile -> LDS (aliases dead sB buf0)
#pragma unroll
  for (int r = 0; r < 4; ++r)
#pragma unroll
    for (int ct = 0; ct < 4; ++ct)
      Yl[(wv * 16 + 4 * g + r) * 64 + ct * 16 + l15] = acc[ct][r];
  __syncthreads();

  // fold: oadj_part[b][nt] = S_tile^T @ Y_tile  (f32)
  const int kq = tid >> 4, lq = tid & 15;
  f32x4 a2[4] = {};
  for (int r = 0; r < 64; ++r) {
    f32x4 s4 = *(const f32x4*)(sl + r * 64 + kq * 4);
    f32x4 y4 = *(const f32x4*)(Yl + r * 64 + lq * 4);
#pragma unroll
    for (int i = 0; i < 4; ++i)
#pragma unroll
      for (int j = 0; j < 4; ++j) a2[i][j] += s4[i] * y4[j];
  }
  float* op = oadj_part + ((size_t)(b * 64 + nt)) * 4096;
#pragma unroll
  for (int i = 0; i < 4; ++i)
    *(f32x4*)(op + (kq * 4 + i) * 64 + lq * 4) = a2[i];
}

// ---------------------------------------------------------------- k_small
// partials of ss = S^T S and pooled = S^T X. grid 128 (b&7, chunk of 256 rows).
__global__ __launch_bounds__(256) void k_small(
    const float* __restrict__ s_out, const float* __restrict__ x,
    float* __restrict__ ss_part, float* __restrict__ p_part) {
  __shared__ __align__(16) float sc[32 * 64];
  __shared__ __align__(16) float xc[32 * 128];
  const int b = blockIdx.x & 7;
  const int ch = blockIdx.x >> 3;
  const int tid = threadIdx.x;
  const int kq = tid >> 4, cq = tid & 15;
  f32x4 ssa[4] = {};
  f32x4 pa[8] = {};
  for (int sub = 0; sub < 8; ++sub) {
    if (sub) __syncthreads();
    const int nb = ch * 256 + sub * 32;
    stage_lds<2>(s_out + ((size_t)(b * 4096 + nb)) * 64, sc, tid);
    stage_lds<4>(x + ((size_t)(b * 4096 + nb)) * 128, xc, tid);
    __syncthreads();
    for (int n = 0; n < 32; ++n) {
      f32x4 s4 = *(const f32x4*)(sc + n * 64 + kq * 4);
      f32x4 s4b = *(const f32x4*)(sc + n * 64 + cq * 4);
      f32x4 x4a = *(const f32x4*)(xc + n * 128 + cq * 8);
      f32x4 x4b = *(const f32x4*)(xc + n * 128 + cq * 8 + 4);
#pragma unroll
      for (int i = 0; i < 4; ++i) {
#pragma unroll
        for (int j = 0; j < 4; ++j) {
          ssa[i][j] += s4[i] * s4b[j];
          pa[i * 2][j] += s4[i] * x4a[j];
          pa[i * 2 + 1][j] += s4[i] * x4b[j];
        }
      }
    }
  }
  float* sp = ss_part + ((size_t)(b * 16 + ch)) * 4096;
  float* pp = p_part + ((size_t)(b * 16 + ch)) * 8192;
#pragma unroll
  for (int i = 0; i < 4; ++i) {
    *(f32x4*)(sp + (kq * 4 + i) * 64 + cq * 4) = ssa[i];
    *(f32x4*)(pp + (kq * 4 + i) * 128 + cq * 8) = pa[i * 2];
    *(f32x4*)(pp + (kq * 4 + i) * 128 + cq * 8 + 4) = pa[i * 2 + 1];
  }
}

// ---------------------------------------------------------------- k_reduce
__global__ __launch_bounds__(256) void k_reduce(
    const float* __restrict__ oadj_part, const float* __restrict__ ss_part,
    const float* __restrict__ p_part, float* __restrict__ oadj_raw,
    float* __restrict__ ss_sum, float* __restrict__ out_feat) {
  const int gid = blockIdx.x * 256 + threadIdx.x;
  if (gid < 32768) {
    int b = gid >> 12, e = gid & 4095;
    float s = 0.f;
    for (int t = 0; t < 64; ++t) s += oadj_part[((size_t)(b * 64 + t)) * 4096 + e];
    oadj_raw[gid] = s;
  } else if (gid < 65536) {
    int g2 = gid - 32768, b = g2 >> 12, e = g2 & 4095;
    float s = 0.f;
    for (int t = 0; t < 16; ++t) s += ss_part[((size_t)(b * 16 + t)) * 4096 + e];
    ss_sum[g2] = s;
  } else {
    int g3 = gid - 65536, b = g3 >> 13, e = g3 & 8191;
    float s = 0.f;
    for (int t = 0; t < 16; ++t) s += p_part[((size_t)(b * 16 + t)) * 8192 + e];
    const float scale = 1.0507009873554805f, alpha = 1.6732632423543772f;
    out_feat[g3] = s > 0.f ? scale * s : scale * alpha * (expf(s) - 1.f);
  }
}

// ---------------------------------------------------------------- k_finalize
__global__ __launch_bounds__(256) void k_finalize(
    const float* __restrict__ oadj_raw, const float* __restrict__ ss_sum,
    const float* __restrict__ deg, const float* __restrict__ s_out,
    float* __restrict__ out_adj, float* __restrict__ loss_part) {
  __shared__ float red[256];
  __shared__ float q1[4][64], q2[4][64];
  __shared__ float ca[64], dvec[64];
  __shared__ float sh_scalar;
  const int b = blockIdx.x, t = threadIdx.x;
  const float* degb = deg + b * 4096;
  const float* ob = oadj_raw + b * 4096;
  const float* ssb = ss_sum + b * 4096;

  float p = 0.f;
  for (int i = t; i < 4096; i += 256) p += degb[i];
  red[t] = p; __syncthreads();
  for (int o = 128; o > 0; o >>= 1) { if (t < o) red[t] += red[t + o]; __syncthreads(); }
  if (t == 0) sh_scalar = red[0];
  __syncthreads();
  const float sm = sh_scalar;
  __syncthreads();

  const int k = t & 63, q = t >> 6;
  const float* sb = s_out + (size_t)b * 4096 * 64;
  float cs = 0.f, cac = 0.f;
  for (int n = q; n < 4096; n += 4) {
    float sv = sb[(size_t)n * 64 + k];
    cs += sv; cac += sv * degb[n];
  }
  q1[q][k] = cs; q2[q][k] = cac;
  __syncthreads();
  float csize_k = 0.f;
  if (t < 64) {
    csize_k = q1[0][t] + q1[1][t] + q1[2][t] + q1[3][t];
    ca[t] = q2[0][t] + q2[1][t] + q2[2][t] + q2[3][t];
  }
  __syncthreads();

  float tp = 0.f;
  if (t < 64) { float dg = ob[t * 64 + t]; tp = dg - ca[t] * ca[t] / sm; }
  red[t] = tp; __syncthreads();
  for (int o = 128; o > 0; o >>= 1) { if (t < o) red[t] += red[t + o]; __syncthreads(); }
  const float spectral_b = -red[0] / sm;
  __syncthreads();

  float fp = 0.f;
  for (int i = t; i < 4096; i += 256) { float v = ssb[i]; fp += v * v; }
  red[t] = fp; __syncthreads();
  for (int o = 128; o > 0; o >>= 1) { if (t < o) red[t] += red[t + o]; __syncthreads(); }
  const float fro = sqrtf(red[0]);
  __syncthreads();
  float op2 = 0.f;
  for (int i = t; i < 4096; i += 256) {
    float v = ssb[i] / fro - (((i >> 6) == (i & 63)) ? 0.125f : 0.f);
    op2 += v * v;
  }
  red[t] = op2; __syncthreads();
  for (int o = 128; o > 0; o >>= 1) { if (t < o) red[t] += red[t + o]; __syncthreads(); }
  const float ortho_b = sqrtf(red[0]);
  __syncthreads();

  red[t] = (t < 64) ? csize_k * csize_k : 0.f;
  __syncthreads();
  for (int o = 128; o > 0; o >>= 1) { if (t < o) red[t] += red[t + o]; __syncthreads(); }
  const float cluster_b = sqrtf(red[0]) * 8.f / 4096.f - 1.f;
  __syncthreads();

  float rp = 0.f;
  {
    const float* orow = ob + k * 64;
    for (int lc = q * 16; lc < q * 16 + 16; ++lc)
      if (lc != k) rp += orow[lc];
  }
  q1[q][k] = rp; __syncthreads();
  if (t < 64) dvec[t] = sqrtf(q1[0][t] + q1[1][t] + q1[2][t] + q1[3][t]) + 1e-15f;
  __syncthreads();
  for (int i = t; i < 4096; i += 256) {
    int kk = i >> 6, lc = i & 63;
    float v = (kk == lc) ? 0.f : ob[i] / (dvec[kk] * dvec[lc]);
    out_adj[(size_t)b * 4096 + i] = v;
  }
  if (t == 0) {
    loss_part[b * 3 + 0] = spectral_b;
    loss_part[b * 3 + 1] = ortho_b;
    loss_part[b * 3 + 2] = cluster_b;
  }
}

__global__ void k_scalars(const float* __restrict__ lp, float* __restrict__ o3) {
  if (threadIdx.x == 0) {
    float s = 0.f, o = 0.f, c = 0.f;
    for (int b = 0; b < 8; ++b) { s += lp[b * 3]; o += lp[b * 3 + 1]; c += lp[b * 3 + 2]; }
    o3[0] = s * 0.125f; o3[1] = o * 0.125f; o3[2] = c * 0.125f;
  }
}

extern "C" void kernel_launch(void* const* d_in, const int* in_sizes, int n_in,
                              void* d_out, int out_size, void* d_ws, size_t ws_size,
                              hipStream_t stream) {
  const float* x = (const float*)d_in[0];
  const float* adj = (const float*)d_in[1];
  const float* w = (const float*)d_in[2];
  const float* bias = (const float*)d_in[3];
  float* out = (float*)d_out;
  float* s_out = out;                       // [8,4096,64]
  float* out_feat = out + 2097152;          // [8,64,128]
  float* out_adj = out + 2162688;           // [8,64,64]
  float* out_sc = out + 2195456;            // 3 scalars

  char* ws = (char*)d_ws;
  _Float16* sB = (_Float16*)ws;                              // 8 MB
  float* oadj_part = (float*)(ws + (8u << 20));              // 8 MB
  float* ss_part = (float*)(ws + (16u << 20));               // 2 MB
  float* p_part = (float*)(ws + (20u << 20));                // 4 MB
  float* deg = (float*)(ws + (28u << 20));                   // 128 KB
  float* oadj_raw = (float*)(ws + (28u << 20) + (128u << 10));
  float* ss_sum = (float*)(ws + (28u << 20) + (256u << 10));
  float* loss_part = (float*)(ws + (28u << 20) + (384u << 10));

  k_assign<<<dim3(512), dim3(256), 0, stream>>>(x, w, bias, s_out, sB);
  k_big<<<dim3(512), dim3(256), 0, stream>>>(adj, sB, s_out, deg, oadj_part);
  k_small<<<dim3(128), dim3(256), 0, stream>>>(s_out, x, ss_part, p_part);
  k_reduce<<<dim3(512), dim3(256), 0, stream>>>(oadj_part, ss_part, p_part,
                                                oadj_raw, ss_sum, out_feat);
  k_finalize<<<dim3(8), dim3(256), 0, stream>>>(oadj_raw, ss_sum, deg, s_out,
                                                out_adj, loss_part);
  k_scalars<<<dim3(1), dim3(64), 0, stream>>>(loss_part, out_sc);
}

// Round 4
// 218.945 us; speedup vs baseline: 2.1065x; 1.6657x over previous
//
#include <hip/hip_runtime.h>
#include <hip/hip_bf16.h>

// DMoN pooling, MI355X. B=8, N=4096, C=128, K=64.
//  k_assign : s = softmax(x@W+b) via fp16-split MFMA; writes s (f32) + packed
//             S fragments (fp16 hi only) in MFMA B-layout.
//  k_big    : Y = adj @ S, barrier-free main loop, adj 2-phase register
//             prefetch; frag loads issued BEFORE adj prefetch so MFMA waits at
//             vmcnt(4) and adj stays in flight (R2 had this inverted).
//             deg rowsum free; epilogue folds oadj_part = S_tile^T @ Y_tile.
//  k_small  : partials of ss = S^T S, pooled = S^T X, csize = colsum(S),
//             ca = S^T deg  (moved out of k_finalize: 128 blocks vs 8).
//  k_reduce / k_finalize / k_scalars: reduce partials, losses, normalize.
// All reductions deterministic (fixed-order partials, no FP atomics).

typedef _Float16 f16x8 __attribute__((ext_vector_type(8)));
typedef float f32x4 __attribute__((ext_vector_type(4)));

#define MFMA16(a, b, c) __builtin_amdgcn_mfma_f32_16x16x32_f16((a), (b), (c), 0, 0, 0)

__device__ __forceinline__ void gld_lds16(const void* g, void* l) {
  __builtin_amdgcn_global_load_lds(
      (const __attribute__((address_space(1))) void*)g,
      (__attribute__((address_space(3))) void*)l, 16, 0, 0);
}

template <int NCHUNK>
__device__ __forceinline__ void stage_lds(const void* g, void* lbase, int tid) {
  char* ld = (char*)lbase + (tid >> 6) * 1024;   // wave-uniform base; HW adds lane*16
  const char* gs = (const char*)g + tid * 16;
#pragma unroll
  for (int p = 0; p < NCHUNK; ++p)
    gld_lds16(gs + p * 4096, ld + p * 4096);
}

// ---------------------------------------------------------------- k_assign
__global__ __launch_bounds__(256) void k_assign(
    const float* __restrict__ x, const float* __restrict__ w,
    const float* __restrict__ bias, float* __restrict__ s_out,
    _Float16* __restrict__ sB) {
  __shared__ __align__(16) _Float16 wT[2][64][136];
  __shared__ __align__(16) float sT[64][76];
  const int b = blockIdx.x & 7;
  const int it = blockIdx.x >> 3;
  const int n_base = it * 64;
  const int tid = threadIdx.x;

  for (int idx = tid; idx < 8192; idx += 256) {
    int c = idx >> 6, k = idx & 63;
    float v = w[idx];
    _Float16 h = (_Float16)v;
    wT[0][k][c] = h;
    wT[1][k][c] = (_Float16)(v - (float)h);
  }
  const int l = tid & 63, wv = tid >> 6;
  const int l15 = l & 15, g = l >> 4;
  float bv[4];
#pragma unroll
  for (int ct = 0; ct < 4; ++ct) bv[ct] = bias[ct * 16 + l15];
  __syncthreads();

  f32x4 acc[4];
#pragma unroll
  for (int ct = 0; ct < 4; ++ct) acc[ct] = (f32x4){bv[ct], bv[ct], bv[ct], bv[ct]};

  const float* xrow = x + ((size_t)(b * 4096 + n_base + wv * 16 + l15)) * 128;
#pragma unroll
  for (int cs = 0; cs < 4; ++cs) {
    const int c0 = cs * 32;
    f32x4 r0 = *(const f32x4*)(xrow + c0 + 8 * g);
    f32x4 r1 = *(const f32x4*)(xrow + c0 + 8 * g + 4);
    f16x8 ah, al;
#pragma unroll
    for (int j = 0; j < 4; ++j) {
      float v0 = r0[j]; _Float16 h0 = (_Float16)v0;
      ah[j] = h0; al[j] = (_Float16)(v0 - (float)h0);
      float v1 = r1[j]; _Float16 h1 = (_Float16)v1;
      ah[4 + j] = h1; al[4 + j] = (_Float16)(v1 - (float)h1);
    }
#pragma unroll
    for (int ct = 0; ct < 4; ++ct) {
      f16x8 bh = *(const f16x8*)&wT[0][ct * 16 + l15][c0 + 8 * g];
      f16x8 bl = *(const f16x8*)&wT[1][ct * 16 + l15][c0 + 8 * g];
      acc[ct] = MFMA16(ah, bh, acc[ct]);
      acc[ct] = MFMA16(al, bh, acc[ct]);
      acc[ct] = MFMA16(ah, bl, acc[ct]);
    }
  }

#pragma unroll
  for (int r = 0; r < 4; ++r) {
    float m = fmaxf(fmaxf(acc[0][r], acc[1][r]), fmaxf(acc[2][r], acc[3][r]));
#pragma unroll
    for (int off = 1; off < 16; off <<= 1) m = fmaxf(m, __shfl_xor(m, off, 64));
    float e[4], sum = 0.f;
#pragma unroll
    for (int ct = 0; ct < 4; ++ct) { e[ct] = __expf(acc[ct][r] - m); sum += e[ct]; }
#pragma unroll
    for (int off = 1; off < 16; off <<= 1) sum += __shfl_xor(sum, off, 64);
    float inv = 1.0f / sum;
#pragma unroll
    for (int ct = 0; ct < 4; ++ct) acc[ct][r] = e[ct] * inv;
  }

  const int row_l = wv * 16 + 4 * g;
  float* srow = s_out + ((size_t)(b * 4096 + n_base)) * 64;
#pragma unroll
  for (int r = 0; r < 4; ++r)
#pragma unroll
    for (int ct = 0; ct < 4; ++ct) {
      srow[(size_t)(row_l + r) * 64 + ct * 16 + l15] = acc[ct][r];
      sT[ct * 16 + l15][row_l + r] = acc[ct][r];
    }
  __syncthreads();

  // repack to B-fragment layout (hi only): [ks][ct][lane][8] fp16
  _Float16* dst = sB + (size_t)(b * 64 + it) * 4096;
#pragma unroll
  for (int p = 0; p < 2; ++p) {
    int slot = tid + 256 * p;                 // 0..511
    int ks = slot >> 8, ct = (slot >> 6) & 3, ln = slot & 63;
    int col = ct * 16 + (ln & 15);
    int row0 = ks * 32 + 8 * (ln >> 4);
    f16x8 o;
#pragma unroll
    for (int j = 0; j < 8; ++j) o[j] = (_Float16)sT[col][row0 + j];
    *(f16x8*)(dst + slot * 8) = o;
  }
}

// ---------------------------------------------------------------- k_big
// grid 512 (b = blockIdx&7 -> XCD pin, nt = blockIdx>>3), block 256.
// Barrier-free; frag loads FIRST, then adj prefetch (in-order vmcnt keeps
// adj in flight across the MFMAs -> wait is vmcnt(4), never 0).
__global__ __launch_bounds__(256) void k_big(
    const float* __restrict__ adj, const _Float16* __restrict__ sB,
    const float* __restrict__ s_out, float* __restrict__ deg,
    float* __restrict__ oadj_part) {
  __shared__ __align__(16) float sl[4096];
  __shared__ __align__(16) float Yl[4096];
  const int b = blockIdx.x & 7;
  const int nt = blockIdx.x >> 3;
  const int n_base = nt * 64;
  const int tid = threadIdx.x;
  const int l = tid & 63, wv = tid >> 6;
  const int l15 = l & 15, g = l >> 4;

  stage_lds<4>(s_out + ((size_t)(b * 4096 + n_base)) * 64, sl, tid);

  const f16x8* fbase = (const f16x8*)(sB + (size_t)b * 64 * 4096) + l;
  const float* arow =
      adj + ((size_t)b * 4096 + n_base + wv * 16 + l15) * 4096 + 8 * g;

  f32x4 A0, A1, A2, A3, B0, B1, B2, B3;
  A0 = *(const f32x4*)(arow);        A1 = *(const f32x4*)(arow + 4);
  A2 = *(const f32x4*)(arow + 32);   A3 = *(const f32x4*)(arow + 36);
  B0 = *(const f32x4*)(arow + 64);   B1 = *(const f32x4*)(arow + 68);
  B2 = *(const f32x4*)(arow + 96);   B3 = *(const f32x4*)(arow + 100);

  f32x4 acc[4] = {};
  float dacc = 0.f;

  auto phase = [&](f32x4& C0, f32x4& C1, f32x4& C2, f32x4& C3, int itv) {
    const f16x8* fb = fbase + (size_t)itv * 512;
    f16x8 F[8];
#pragma unroll
    for (int q = 0; q < 8; ++q) F[q] = fb[q * 64];   // ALL frag loads first
    f16x8 a0, a1;
#pragma unroll
    for (int j = 0; j < 4; ++j) {
      a0[j] = (_Float16)C0[j]; a0[4 + j] = (_Float16)C1[j];
      a1[j] = (_Float16)C2[j]; a1[4 + j] = (_Float16)C3[j];
    }
    dacc += C0[0] + C0[1] + C0[2] + C0[3] + C1[0] + C1[1] + C1[2] + C1[3] +
            C2[0] + C2[1] + C2[2] + C2[3] + C3[0] + C3[1] + C3[2] + C3[3];
    if (itv + 2 < 64) {  // refill this buffer with iter itv+2 (stays in flight)
      const float* an = arow + (itv + 2) * 64;
      C0 = *(const f32x4*)(an);       C1 = *(const f32x4*)(an + 4);
      C2 = *(const f32x4*)(an + 32);  C3 = *(const f32x4*)(an + 36);
    }
#pragma unroll
    for (int ct = 0; ct < 4; ++ct) acc[ct] = MFMA16(a0, F[ct], acc[ct]);
#pragma unroll
    for (int ct = 0; ct < 4; ++ct) acc[ct] = MFMA16(a1, F[4 + ct], acc[ct]);
  };

#pragma unroll 2
  for (int it = 0; it < 64; it += 2) {
    phase(A0, A1, A2, A3, it);
    phase(B0, B1, B2, B3, it + 1);
  }

  // deg (rowsum of adj), deterministic
  dacc += __shfl_xor(dacc, 16, 64);
  dacc += __shfl_xor(dacc, 32, 64);
  if (l < 16) deg[b * 4096 + n_base + wv * 16 + l] = dacc;

  // Y tile -> LDS
#pragma unroll
  for (int r = 0; r < 4; ++r)
#pragma unroll
    for (int ct = 0; ct < 4; ++ct)
      Yl[(wv * 16 + 4 * g + r) * 64 + ct * 16 + l15] = acc[ct][r];
  __syncthreads();

  // fold: oadj_part[b][nt] = S_tile^T @ Y_tile  (f32)
  const int kq = tid >> 4, lq = tid & 15;
  f32x4 a2[4] = {};
  for (int r = 0; r < 64; ++r) {
    f32x4 s4 = *(const f32x4*)(sl + r * 64 + kq * 4);
    f32x4 y4 = *(const f32x4*)(Yl + r * 64 + lq * 4);
#pragma unroll
    for (int i = 0; i < 4; ++i)
#pragma unroll
      for (int j = 0; j < 4; ++j) a2[i][j] += s4[i] * y4[j];
  }
  float* op = oadj_part + ((size_t)(b * 64 + nt)) * 4096;
#pragma unroll
  for (int i = 0; i < 4; ++i)
    *(f32x4*)(op + (kq * 4 + i) * 64 + lq * 4) = a2[i];
}

// ---------------------------------------------------------------- k_small
// partials of ss = S^T S, pooled = S^T X, csize = colsum(S), ca = S^T deg.
// grid 128 (b&7, chunk of 256 rows).
__global__ __launch_bounds__(256) void k_small(
    const float* __restrict__ s_out, const float* __restrict__ x,
    const float* __restrict__ deg, float* __restrict__ ss_part,
    float* __restrict__ p_part, float* __restrict__ csp,
    float* __restrict__ cap) {
  __shared__ __align__(16) float sc[32 * 64];
  __shared__ __align__(16) float xc[32 * 128];
  __shared__ float qc[4][64], qa[4][64];
  const int b = blockIdx.x & 7;
  const int ch = blockIdx.x >> 3;
  const int tid = threadIdx.x;
  const int kq = tid >> 4, cq = tid & 15;
  const int kk = tid & 63, nq = tid >> 6;
  const float* degb = deg + b * 4096;
  f32x4 ssa[4] = {};
  f32x4 pa[8] = {};
  float csA = 0.f, caA = 0.f;
  for (int sub = 0; sub < 8; ++sub) {
    if (sub) __syncthreads();
    const int nb = ch * 256 + sub * 32;
    stage_lds<2>(s_out + ((size_t)(b * 4096 + nb)) * 64, sc, tid);
    stage_lds<4>(x + ((size_t)(b * 4096 + nb)) * 128, xc, tid);
    __syncthreads();
    for (int n = 0; n < 32; ++n) {
      f32x4 s4 = *(const f32x4*)(sc + n * 64 + kq * 4);
      f32x4 s4b = *(const f32x4*)(sc + n * 64 + cq * 4);
      f32x4 x4a = *(const f32x4*)(xc + n * 128 + cq * 8);
      f32x4 x4b = *(const f32x4*)(xc + n * 128 + cq * 8 + 4);
#pragma unroll
      for (int i = 0; i < 4; ++i) {
#pragma unroll
        for (int j = 0; j < 4; ++j) {
          ssa[i][j] += s4[i] * s4b[j];
          pa[i * 2][j] += s4[i] * x4a[j];
          pa[i * 2 + 1][j] += s4[i] * x4b[j];
        }
      }
    }
    // csize / ca partial for this 32-row chunk
    for (int n = nq; n < 32; n += 4) {
      float sv = sc[n * 64 + kk];
      csA += sv;
      caA += sv * degb[nb + n];
    }
  }
  float* sp = ss_part + ((size_t)(b * 16 + ch)) * 4096;
  float* pp = p_part + ((size_t)(b * 16 + ch)) * 8192;
#pragma unroll
  for (int i = 0; i < 4; ++i) {
    *(f32x4*)(sp + (kq * 4 + i) * 64 + cq * 4) = ssa[i];
    *(f32x4*)(pp + (kq * 4 + i) * 128 + cq * 8) = pa[i * 2];
    *(f32x4*)(pp + (kq * 4 + i) * 128 + cq * 8 + 4) = pa[i * 2 + 1];
  }
  __syncthreads();
  qc[nq][kk] = csA;
  qa[nq][kk] = caA;
  __syncthreads();
  if (tid < 64) {
    csp[(size_t)(b * 16 + ch) * 64 + tid] =
        qc[0][tid] + qc[1][tid] + qc[2][tid] + qc[3][tid];
    cap[(size_t)(b * 16 + ch) * 64 + tid] =
        qa[0][tid] + qa[1][tid] + qa[2][tid] + qa[3][tid];
  }
}

// ---------------------------------------------------------------- k_reduce
__global__ __launch_bounds__(256) void k_reduce(
    const float* __restrict__ oadj_part, const float* __restrict__ ss_part,
    const float* __restrict__ p_part, float* __restrict__ oadj_raw,
    float* __restrict__ ss_sum, float* __restrict__ out_feat) {
  const int gid = blockIdx.x * 256 + threadIdx.x;
  if (gid < 32768) {
    int b = gid >> 12, e = gid & 4095;
    float s = 0.f;
    for (int t = 0; t < 64; ++t) s += oadj_part[((size_t)(b * 64 + t)) * 4096 + e];
    oadj_raw[gid] = s;
  } else if (gid < 65536) {
    int g2 = gid - 32768, b = g2 >> 12, e = g2 & 4095;
    float s = 0.f;
    for (int t = 0; t < 16; ++t) s += ss_part[((size_t)(b * 16 + t)) * 4096 + e];
    ss_sum[g2] = s;
  } else {
    int g3 = gid - 65536, b = g3 >> 13, e = g3 & 8191;
    float s = 0.f;
    for (int t = 0; t < 16; ++t) s += p_part[((size_t)(b * 16 + t)) * 8192 + e];
    const float scale = 1.0507009873554805f, alpha = 1.6732632423543772f;
    out_feat[g3] = s > 0.f ? scale * s : scale * alpha * (expf(s) - 1.f);
  }
}

// ---------------------------------------------------------------- k_finalize
__global__ __launch_bounds__(256) void k_finalize(
    const float* __restrict__ oadj_raw, const float* __restrict__ ss_sum,
    const float* __restrict__ deg, const float* __restrict__ csp,
    const float* __restrict__ cap, float* __restrict__ out_adj,
    float* __restrict__ loss_part) {
  __shared__ float red[256];
  __shared__ float q1[4][64];
  __shared__ float ca[64], dvec[64];
  __shared__ float sh_scalar;
  const int b = blockIdx.x, t = threadIdx.x;
  const float* degb = deg + b * 4096;
  const float* ob = oadj_raw + b * 4096;
  const float* ssb = ss_sum + b * 4096;

  float p = 0.f;
  for (int i = t; i < 4096; i += 256) p += degb[i];
  red[t] = p; __syncthreads();
  for (int o = 128; o > 0; o >>= 1) { if (t < o) red[t] += red[t + o]; __syncthreads(); }
  if (t == 0) sh_scalar = red[0];
  __syncthreads();
  const float sm = sh_scalar;
  __syncthreads();

  // csize, ca from k_small partials (16 chunks x 64)
  float csize_k = 0.f;
  if (t < 64) {
    float cs = 0.f, cac = 0.f;
    for (int ch = 0; ch < 16; ++ch) {
      cs += csp[(size_t)(b * 16 + ch) * 64 + t];
      cac += cap[(size_t)(b * 16 + ch) * 64 + t];
    }
    csize_k = cs;
    ca[t] = cac;
  }
  __syncthreads();

  float tp = 0.f;
  if (t < 64) { float dg = ob[t * 64 + t]; tp = dg - ca[t] * ca[t] / sm; }
  red[t] = tp; __syncthreads();
  for (int o = 128; o > 0; o >>= 1) { if (t < o) red[t] += red[t + o]; __syncthreads(); }
  const float spectral_b = -red[0] / sm;
  __syncthreads();

  float fp = 0.f;
  for (int i = t; i < 4096; i += 256) { float v = ssb[i]; fp += v * v; }
  red[t] = fp; __syncthreads();
  for (int o = 128; o > 0; o >>= 1) { if (t < o) red[t] += red[t + o]; __syncthreads(); }
  const float fro = sqrtf(red[0]);
  __syncthreads();
  float op2 = 0.f;
  for (int i = t; i < 4096; i += 256) {
    float v = ssb[i] / fro - (((i >> 6) == (i & 63)) ? 0.125f : 0.f);
    op2 += v * v;
  }
  red[t] = op2; __syncthreads();
  for (int o = 128; o > 0; o >>= 1) { if (t < o) red[t] += red[t + o]; __syncthreads(); }
  const float ortho_b = sqrtf(red[0]);
  __syncthreads();

  red[t] = (t < 64) ? csize_k * csize_k : 0.f;
  __syncthreads();
  for (int o = 128; o > 0; o >>= 1) { if (t < o) red[t] += red[t + o]; __syncthreads(); }
  const float cluster_b = sqrtf(red[0]) * 8.f / 4096.f - 1.f;
  __syncthreads();

  float rp = 0.f;
  {
    const int k = t & 63, q = t >> 6;
    const float* orow = ob + k * 64;
    for (int lc = q * 16; lc < q * 16 + 16; ++lc)
      if (lc != k) rp += orow[lc];
    q1[q][k] = rp;
  }
  __syncthreads();
  if (t < 64) dvec[t] = sqrtf(q1[0][t] + q1[1][t] + q1[2][t] + q1[3][t]) + 1e-15f;
  __syncthreads();
  for (int i = t; i < 4096; i += 256) {
    int kk = i >> 6, lc = i & 63;
    float v = (kk == lc) ? 0.f : ob[i] / (dvec[kk] * dvec[lc]);
    out_adj[(size_t)b * 4096 + i] = v;
  }
  if (t == 0) {
    loss_part[b * 3 + 0] = spectral_b;
    loss_part[b * 3 + 1] = ortho_b;
    loss_part[b * 3 + 2] = cluster_b;
  }
}

__global__ void k_scalars(const float* __restrict__ lp, float* __restrict__ o3) {
  if (threadIdx.x == 0) {
    float s = 0.f, o = 0.f, c = 0.f;
    for (int b = 0; b < 8; ++b) { s += lp[b * 3]; o += lp[b * 3 + 1]; c += lp[b * 3 + 2]; }
    o3[0] = s * 0.125f; o3[1] = o * 0.125f; o3[2] = c * 0.125f;
  }
}

extern "C" void kernel_launch(void* const* d_in, const int* in_sizes, int n_in,
                              void* d_out, int out_size, void* d_ws, size_t ws_size,
                              hipStream_t stream) {
  const float* x = (const float*)d_in[0];
  const float* adj = (const float*)d_in[1];
  const float* w = (const float*)d_in[2];
  const float* bias = (const float*)d_in[3];
  float* out = (float*)d_out;
  float* s_out = out;                       // [8,4096,64]
  float* out_feat = out + 2097152;          // [8,64,128]
  float* out_adj = out + 2162688;           // [8,64,64]
  float* out_sc = out + 2195456;            // 3 scalars

  char* ws = (char*)d_ws;
  _Float16* sB = (_Float16*)ws;                              // 4 MB
  float* oadj_part = (float*)(ws + (8u << 20));              // 8 MB
  float* ss_part = (float*)(ws + (16u << 20));               // 2 MB
  float* p_part = (float*)(ws + (20u << 20));                // 4 MB
  float* deg = (float*)(ws + (28u << 20));                   // 128 KB
  float* oadj_raw = (float*)(ws + (28u << 20) + (128u << 10));
  float* ss_sum = (float*)(ws + (28u << 20) + (256u << 10));
  float* loss_part = (float*)(ws + (28u << 20) + (384u << 10));
  float* csp = (float*)(ws + (28u << 20) + (512u << 10));    // 32 KB
  float* cap = (float*)(ws + (28u << 20) + (640u << 10));    // 32 KB

  k_assign<<<dim3(512), dim3(256), 0, stream>>>(x, w, bias, s_out, sB);
  k_big<<<dim3(512), dim3(256), 0, stream>>>(adj, sB, s_out, deg, oadj_part);
  k_small<<<dim3(128), dim3(256), 0, stream>>>(s_out, x, deg, ss_part, p_part,
                                               csp, cap);
  k_reduce<<<dim3(512), dim3(256), 0, stream>>>(oadj_part, ss_part, p_part,
                                                oadj_raw, ss_sum, out_feat);
  k_finalize<<<dim3(8), dim3(256), 0, stream>>>(oadj_raw, ss_sum, deg, csp, cap,
                                                out_adj, loss_part);
  k_scalars<<<dim3(1), dim3(64), 0, stream>>>(loss_part, out_sc);
}

// Round 5
// 209.822 us; speedup vs baseline: 2.1981x; 1.0435x over previous
//
#include <hip/hip_runtime.h>
#include <hip/hip_bf16.h>

// DMoN pooling, MI355X. B=8, N=4096, C=128, K=64.
//  k_assign : s = softmax(x@W+b) via fp16-split MFMA; writes s (f32) + packed
//             S fragments (fp16 hi only) in MFMA B-layout.
//  k_big    : Y = adj @ S, barrier-free main loop, 512 thr/block (16 waves/CU):
//             wave = (row-seg 0..3, col-half 0..1), 32 phases/wave, adj 2-phase
//             register prefetch, frag loads issued before adj prefetch (MFMA
//             waits vmcnt(4), adj stays in flight). Epilogue merges col-half
//             accs in LDS and folds oadj_part = S_tile^T @ Y_tile.
//  k_small  : partials of ss = S^T S, pooled = S^T X, csize = colsum(S).
//  k_reduce / k_finalize / k_scalars: reduce partials, losses, normalize.
//  deg is never materialized: rows of softmax sum to 1 =>
//    ca = rowsum(oadj_raw), 2m = sum(oadj_raw).
// All reductions deterministic (fixed-order partials, no FP atomics).

typedef _Float16 f16x8 __attribute__((ext_vector_type(8)));
typedef float f32x4 __attribute__((ext_vector_type(4)));

#define MFMA16(a, b, c) __builtin_amdgcn_mfma_f32_16x16x32_f16((a), (b), (c), 0, 0, 0)

__device__ __forceinline__ void gld_lds16(const void* g, void* l) {
  __builtin_amdgcn_global_load_lds(
      (const __attribute__((address_space(1))) void*)g,
      (__attribute__((address_space(3))) void*)l, 16, 0, 0);
}

template <int NCHUNK>
__device__ __forceinline__ void stage_lds(const void* g, void* lbase, int tid) {
  char* ld = (char*)lbase + (tid >> 6) * 1024;   // wave-uniform base; HW adds lane*16
  const char* gs = (const char*)g + tid * 16;
#pragma unroll
  for (int p = 0; p < NCHUNK; ++p)
    gld_lds16(gs + p * 4096, ld + p * 4096);
}

// ---------------------------------------------------------------- k_assign
__global__ __launch_bounds__(256) void k_assign(
    const float* __restrict__ x, const float* __restrict__ w,
    const float* __restrict__ bias, float* __restrict__ s_out,
    _Float16* __restrict__ sB) {
  __shared__ __align__(16) _Float16 wT[2][64][136];
  __shared__ __align__(16) float sT[64][76];
  const int b = blockIdx.x & 7;
  const int it = blockIdx.x >> 3;
  const int n_base = it * 64;
  const int tid = threadIdx.x;

  for (int idx = tid; idx < 8192; idx += 256) {
    int c = idx >> 6, k = idx & 63;
    float v = w[idx];
    _Float16 h = (_Float16)v;
    wT[0][k][c] = h;
    wT[1][k][c] = (_Float16)(v - (float)h);
  }
  const int l = tid & 63, wv = tid >> 6;
  const int l15 = l & 15, g = l >> 4;
  float bv[4];
#pragma unroll
  for (int ct = 0; ct < 4; ++ct) bv[ct] = bias[ct * 16 + l15];
  __syncthreads();

  f32x4 acc[4];
#pragma unroll
  for (int ct = 0; ct < 4; ++ct) acc[ct] = (f32x4){bv[ct], bv[ct], bv[ct], bv[ct]};

  const float* xrow = x + ((size_t)(b * 4096 + n_base + wv * 16 + l15)) * 128;
#pragma unroll
  for (int cs = 0; cs < 4; ++cs) {
    const int c0 = cs * 32;
    f32x4 r0 = *(const f32x4*)(xrow + c0 + 8 * g);
    f32x4 r1 = *(const f32x4*)(xrow + c0 + 8 * g + 4);
    f16x8 ah, al;
#pragma unroll
    for (int j = 0; j < 4; ++j) {
      float v0 = r0[j]; _Float16 h0 = (_Float16)v0;
      ah[j] = h0; al[j] = (_Float16)(v0 - (float)h0);
      float v1 = r1[j]; _Float16 h1 = (_Float16)v1;
      ah[4 + j] = h1; al[4 + j] = (_Float16)(v1 - (float)h1);
    }
#pragma unroll
    for (int ct = 0; ct < 4; ++ct) {
      f16x8 bh = *(const f16x8*)&wT[0][ct * 16 + l15][c0 + 8 * g];
      f16x8 bl = *(const f16x8*)&wT[1][ct * 16 + l15][c0 + 8 * g];
      acc[ct] = MFMA16(ah, bh, acc[ct]);
      acc[ct] = MFMA16(al, bh, acc[ct]);
      acc[ct] = MFMA16(ah, bl, acc[ct]);
    }
  }

#pragma unroll
  for (int r = 0; r < 4; ++r) {
    float m = fmaxf(fmaxf(acc[0][r], acc[1][r]), fmaxf(acc[2][r], acc[3][r]));
#pragma unroll
    for (int off = 1; off < 16; off <<= 1) m = fmaxf(m, __shfl_xor(m, off, 64));
    float e[4], sum = 0.f;
#pragma unroll
    for (int ct = 0; ct < 4; ++ct) { e[ct] = __expf(acc[ct][r] - m); sum += e[ct]; }
#pragma unroll
    for (int off = 1; off < 16; off <<= 1) sum += __shfl_xor(sum, off, 64);
    float inv = 1.0f / sum;
#pragma unroll
    for (int ct = 0; ct < 4; ++ct) acc[ct][r] = e[ct] * inv;
  }

  const int row_l = wv * 16 + 4 * g;
  float* srow = s_out + ((size_t)(b * 4096 + n_base)) * 64;
#pragma unroll
  for (int r = 0; r < 4; ++r)
#pragma unroll
    for (int ct = 0; ct < 4; ++ct) {
      srow[(size_t)(row_l + r) * 64 + ct * 16 + l15] = acc[ct][r];
      sT[ct * 16 + l15][row_l + r] = acc[ct][r];
    }
  __syncthreads();

  // repack to B-fragment layout (hi only): [ks][ct][lane][8] fp16
  _Float16* dst = sB + (size_t)(b * 64 + it) * 4096;
#pragma unroll
  for (int p = 0; p < 2; ++p) {
    int slot = tid + 256 * p;                 // 0..511
    int ks = slot >> 8, ct = (slot >> 6) & 3, ln = slot & 63;
    int col = ct * 16 + (ln & 15);
    int row0 = ks * 32 + 8 * (ln >> 4);
    f16x8 o;
#pragma unroll
    for (int j = 0; j < 8; ++j) o[j] = (_Float16)sT[col][row0 + j];
    *(f16x8*)(dst + slot * 8) = o;
  }
}

// ---------------------------------------------------------------- k_big
// grid 512 (b = blockIdx&7 -> XCD pin, nt = blockIdx>>3), block 512 (8 waves).
// wave w: row-seg wr = w&3 (16 rows), col-half kh = w>>2 (2048 cols, 32 phases).
__global__ __launch_bounds__(512, 4) void k_big(
    const float* __restrict__ adj, const _Float16* __restrict__ sB,
    const float* __restrict__ s_out, float* __restrict__ oadj_part) {
  __shared__ __align__(16) float sl[4096];
  __shared__ __align__(16) float Yl[4096];
  const int b = blockIdx.x & 7;
  const int nt = blockIdx.x >> 3;
  const int n_base = nt * 64;
  const int tid = threadIdx.x;
  const int l = tid & 63, w = tid >> 6;
  const int wr = w & 3, kh = w >> 2;
  const int l15 = l & 15, g = l >> 4;

  // stage s tile (16 KB) with 512 threads: two 8 KB passes
  {
    char* ld = (char*)sl + w * 1024;
    const char* gs =
        (const char*)(s_out + ((size_t)(b * 4096 + n_base)) * 64) + tid * 16;
    gld_lds16(gs, ld);
    gld_lds16(gs + 8192, ld + 8192);
  }

  const f16x8* fbase =
      (const f16x8*)(sB + (size_t)b * 64 * 4096) + (size_t)kh * 32 * 512 + l;
  const float* arow = adj + ((size_t)b * 4096 + n_base + wr * 16 + l15) * 4096 +
                      kh * 2048 + 8 * g;

  f32x4 A0, A1, A2, A3, B0, B1, B2, B3;
  A0 = *(const f32x4*)(arow);        A1 = *(const f32x4*)(arow + 4);
  A2 = *(const f32x4*)(arow + 32);   A3 = *(const f32x4*)(arow + 36);
  B0 = *(const f32x4*)(arow + 64);   B1 = *(const f32x4*)(arow + 68);
  B2 = *(const f32x4*)(arow + 96);   B3 = *(const f32x4*)(arow + 100);

  f32x4 acc[4] = {};

  auto phase = [&](f32x4& C0, f32x4& C1, f32x4& C2, f32x4& C3, int p) {
    const f16x8* fb = fbase + (size_t)p * 512;
    f16x8 F[8];
#pragma unroll
    for (int q = 0; q < 8; ++q) F[q] = fb[q * 64];   // ALL frag loads first
    f16x8 a0, a1;
#pragma unroll
    for (int j = 0; j < 4; ++j) {
      a0[j] = (_Float16)C0[j]; a0[4 + j] = (_Float16)C1[j];
      a1[j] = (_Float16)C2[j]; a1[4 + j] = (_Float16)C3[j];
    }
    if (p + 2 < 32) {  // refill this buffer with phase p+2 (stays in flight)
      const float* an = arow + (p + 2) * 64;
      C0 = *(const f32x4*)(an);       C1 = *(const f32x4*)(an + 4);
      C2 = *(const f32x4*)(an + 32);  C3 = *(const f32x4*)(an + 36);
    }
#pragma unroll
    for (int ct = 0; ct < 4; ++ct) acc[ct] = MFMA16(a0, F[ct], acc[ct]);
#pragma unroll
    for (int ct = 0; ct < 4; ++ct) acc[ct] = MFMA16(a1, F[4 + ct], acc[ct]);
  };

#pragma unroll 2
  for (int p = 0; p < 32; p += 2) {
    phase(A0, A1, A2, A3, p);
    phase(B0, B1, B2, B3, p + 1);
  }

  // merge col-half accumulators into Y tile in LDS
  if (kh == 0) {
#pragma unroll
    for (int r = 0; r < 4; ++r)
#pragma unroll
      for (int ct = 0; ct < 4; ++ct)
        Yl[(wr * 16 + 4 * g + r) * 64 + ct * 16 + l15] = acc[ct][r];
  }
  __syncthreads();
  if (kh == 1) {
#pragma unroll
    for (int r = 0; r < 4; ++r)
#pragma unroll
      for (int ct = 0; ct < 4; ++ct)
        Yl[(wr * 16 + 4 * g + r) * 64 + ct * 16 + l15] += acc[ct][r];
  }
  __syncthreads();

  // fold: oadj_part[b][nt] = S_tile^T @ Y_tile  (f32), 512 threads
  const int kq = tid >> 4, lq = tid & 15;     // kq 0..31, k in {kq, kq+32}
  f32x4 a2a = {}, a2b = {};
  for (int r = 0; r < 64; ++r) {
    float sA = sl[r * 64 + kq];
    float sC = sl[r * 64 + 32 + kq];
    f32x4 y4 = *(const f32x4*)(Yl + r * 64 + lq * 4);
#pragma unroll
    for (int j = 0; j < 4; ++j) { a2a[j] += sA * y4[j]; a2b[j] += sC * y4[j]; }
  }
  float* op = oadj_part + ((size_t)(b * 64 + nt)) * 4096;
  *(f32x4*)(op + kq * 64 + lq * 4) = a2a;
  *(f32x4*)(op + (kq + 32) * 64 + lq * 4) = a2b;
}

// ---------------------------------------------------------------- k_small
// partials of ss = S^T S, pooled = S^T X, csize = colsum(S).
// grid 128 (b&7, chunk of 256 rows).
__global__ __launch_bounds__(256) void k_small(
    const float* __restrict__ s_out, const float* __restrict__ x,
    float* __restrict__ ss_part, float* __restrict__ p_part,
    float* __restrict__ csp) {
  __shared__ __align__(16) float sc[32 * 64];
  __shared__ __align__(16) float xc[32 * 128];
  __shared__ float qc[4][64];
  const int b = blockIdx.x & 7;
  const int ch = blockIdx.x >> 3;
  const int tid = threadIdx.x;
  const int kq = tid >> 4, cq = tid & 15;
  const int kk = tid & 63, nq = tid >> 6;
  f32x4 ssa[4] = {};
  f32x4 pa[8] = {};
  float csA = 0.f;
  for (int sub = 0; sub < 8; ++sub) {
    if (sub) __syncthreads();
    const int nb = ch * 256 + sub * 32;
    stage_lds<2>(s_out + ((size_t)(b * 4096 + nb)) * 64, sc, tid);
    stage_lds<4>(x + ((size_t)(b * 4096 + nb)) * 128, xc, tid);
    __syncthreads();
    for (int n = 0; n < 32; ++n) {
      f32x4 s4 = *(const f32x4*)(sc + n * 64 + kq * 4);
      f32x4 s4b = *(const f32x4*)(sc + n * 64 + cq * 4);
      f32x4 x4a = *(const f32x4*)(xc + n * 128 + cq * 8);
      f32x4 x4b = *(const f32x4*)(xc + n * 128 + cq * 8 + 4);
#pragma unroll
      for (int i = 0; i < 4; ++i) {
#pragma unroll
        for (int j = 0; j < 4; ++j) {
          ssa[i][j] += s4[i] * s4b[j];
          pa[i * 2][j] += s4[i] * x4a[j];
          pa[i * 2 + 1][j] += s4[i] * x4b[j];
        }
      }
    }
    for (int n = nq; n < 32; n += 4) csA += sc[n * 64 + kk];
  }
  float* sp = ss_part + ((size_t)(b * 16 + ch)) * 4096;
  float* pp = p_part + ((size_t)(b * 16 + ch)) * 8192;
#pragma unroll
  for (int i = 0; i < 4; ++i) {
    *(f32x4*)(sp + (kq * 4 + i) * 64 + cq * 4) = ssa[i];
    *(f32x4*)(pp + (kq * 4 + i) * 128 + cq * 8) = pa[i * 2];
    *(f32x4*)(pp + (kq * 4 + i) * 128 + cq * 8 + 4) = pa[i * 2 + 1];
  }
  __syncthreads();
  qc[nq][kk] = csA;
  __syncthreads();
  if (tid < 64)
    csp[(size_t)(b * 16 + ch) * 64 + tid] =
        qc[0][tid] + qc[1][tid] + qc[2][tid] + qc[3][tid];
}

// ---------------------------------------------------------------- k_reduce
__global__ __launch_bounds__(256) void k_reduce(
    const float* __restrict__ oadj_part, const float* __restrict__ ss_part,
    const float* __restrict__ p_part, float* __restrict__ oadj_raw,
    float* __restrict__ ss_sum, float* __restrict__ out_feat) {
  const int gid = blockIdx.x * 256 + threadIdx.x;
  if (gid < 32768) {
    int b = gid >> 12, e = gid & 4095;
    float s = 0.f;
    for (int t = 0; t < 64; ++t) s += oadj_part[((size_t)(b * 64 + t)) * 4096 + e];
    oadj_raw[gid] = s;
  } else if (gid < 65536) {
    int g2 = gid - 32768, b = g2 >> 12, e = g2 & 4095;
    float s = 0.f;
    for (int t = 0; t < 16; ++t) s += ss_part[((size_t)(b * 16 + t)) * 4096 + e];
    ss_sum[g2] = s;
  } else {
    int g3 = gid - 65536, b = g3 >> 13, e = g3 & 8191;
    float s = 0.f;
    for (int t = 0; t < 16; ++t) s += p_part[((size_t)(b * 16 + t)) * 8192 + e];
    const float scale = 1.0507009873554805f, alpha = 1.6732632423543772f;
    out_feat[g3] = s > 0.f ? scale * s : scale * alpha * (expf(s) - 1.f);
  }
}

// ---------------------------------------------------------------- k_finalize
// ca = rowsum(oadj_raw); 2m = sum(oadj_raw)  (softmax rows sum to 1).
__global__ __launch_bounds__(256) void k_finalize(
    const float* __restrict__ oadj_raw, const float* __restrict__ ss_sum,
    const float* __restrict__ csp, float* __restrict__ out_adj,
    float* __restrict__ loss_part) {
  __shared__ float red[256];
  __shared__ float ca[64], dvec[64], diag[64];
  const int b = blockIdx.x, t = threadIdx.x;
  const float* ob = oadj_raw + b * 4096;
  const float* ssb = ss_sum + b * 4096;

  if (t < 64) {
    const float* orow = ob + t * 64;
    float full = 0.f, nod = 0.f;
    for (int lc = 0; lc < 64; ++lc) {
      float v = orow[lc];
      full += v;
      nod += (lc != t) ? v : 0.f;
    }
    ca[t] = full;
    dvec[t] = sqrtf(nod) + 1e-15f;
    diag[t] = orow[t];
  }
  __syncthreads();

  // sm = 2m = sum of all oadj = sum ca
  red[t] = (t < 64) ? ca[t] : 0.f;
  __syncthreads();
  for (int o = 128; o > 0; o >>= 1) { if (t < o) red[t] += red[t + o]; __syncthreads(); }
  const float sm = red[0];
  __syncthreads();

  // spectral: -(sum_k diag - ca^2/sm)/sm
  red[t] = (t < 64) ? (diag[t] - ca[t] * ca[t] / sm) : 0.f;
  __syncthreads();
  for (int o = 128; o > 0; o >>= 1) { if (t < o) red[t] += red[t + o]; __syncthreads(); }
  const float spectral_b = -red[0] / sm;
  __syncthreads();

  // ortho
  float fp = 0.f;
  for (int i = t; i < 4096; i += 256) { float v = ssb[i]; fp += v * v; }
  red[t] = fp; __syncthreads();
  for (int o = 128; o > 0; o >>= 1) { if (t < o) red[t] += red[t + o]; __syncthreads(); }
  const float fro = sqrtf(red[0]);
  __syncthreads();
  float op2 = 0.f;
  for (int i = t; i < 4096; i += 256) {
    float v = ssb[i] / fro - (((i >> 6) == (i & 63)) ? 0.125f : 0.f);
    op2 += v * v;
  }
  red[t] = op2; __syncthreads();
  for (int o = 128; o > 0; o >>= 1) { if (t < o) red[t] += red[t + o]; __syncthreads(); }
  const float ortho_b = sqrtf(red[0]);
  __syncthreads();

  // cluster: csize from csp partials (16 chunks x 64)
  float csize_k = 0.f;
  if (t < 64) {
    for (int ch = 0; ch < 16; ++ch) csize_k += csp[(size_t)(b * 16 + ch) * 64 + t];
  }
  red[t] = (t < 64) ? csize_k * csize_k : 0.f;
  __syncthreads();
  for (int o = 128; o > 0; o >>= 1) { if (t < o) red[t] += red[t + o]; __syncthreads(); }
  const float cluster_b = sqrtf(red[0]) * 8.f / 4096.f - 1.f;
  __syncthreads();

  // normalized out_adj (diag zeroed)
  for (int i = t; i < 4096; i += 256) {
    int kk = i >> 6, lc = i & 63;
    float v = (kk == lc) ? 0.f : ob[i] / (dvec[kk] * dvec[lc]);
    out_adj[(size_t)b * 4096 + i] = v;
  }
  if (t == 0) {
    loss_part[b * 3 + 0] = spectral_b;
    loss_part[b * 3 + 1] = ortho_b;
    loss_part[b * 3 + 2] = cluster_b;
  }
}

__global__ void k_scalars(const float* __restrict__ lp, float* __restrict__ o3) {
  if (threadIdx.x == 0) {
    float s = 0.f, o = 0.f, c = 0.f;
    for (int b = 0; b < 8; ++b) { s += lp[b * 3]; o += lp[b * 3 + 1]; c += lp[b * 3 + 2]; }
    o3[0] = s * 0.125f; o3[1] = o * 0.125f; o3[2] = c * 0.125f;
  }
}

extern "C" void kernel_launch(void* const* d_in, const int* in_sizes, int n_in,
                              void* d_out, int out_size, void* d_ws, size_t ws_size,
                              hipStream_t stream) {
  const float* x = (const float*)d_in[0];
  const float* adj = (const float*)d_in[1];
  const float* w = (const float*)d_in[2];
  const float* bias = (const float*)d_in[3];
  float* out = (float*)d_out;
  float* s_out = out;                       // [8,4096,64]
  float* out_feat = out + 2097152;          // [8,64,128]
  float* out_adj = out + 2162688;           // [8,64,64]
  float* out_sc = out + 2195456;            // 3 scalars

  char* ws = (char*)d_ws;
  _Float16* sB = (_Float16*)ws;                              // 4 MB
  float* oadj_part = (float*)(ws + (8u << 20));              // 8 MB
  float* ss_part = (float*)(ws + (16u << 20));               // 2 MB
  float* p_part = (float*)(ws + (20u << 20));                // 4 MB
  float* oadj_raw = (float*)(ws + (28u << 20) + (128u << 10));
  float* ss_sum = (float*)(ws + (28u << 20) + (256u << 10));
  float* loss_part = (float*)(ws + (28u << 20) + (384u << 10));
  float* csp = (float*)(ws + (28u << 20) + (512u << 10));    // 32 KB

  k_assign<<<dim3(512), dim3(256), 0, stream>>>(x, w, bias, s_out, sB);
  k_big<<<dim3(512), dim3(512), 0, stream>>>(adj, sB, s_out, oadj_part);
  k_small<<<dim3(128), dim3(256), 0, stream>>>(s_out, x, ss_part, p_part, csp);
  k_reduce<<<dim3(512), dim3(256), 0, stream>>>(oadj_part, ss_part, p_part,
                                                oadj_raw, ss_sum, out_feat);
  k_finalize<<<dim3(8), dim3(256), 0, stream>>>(oadj_raw, ss_sum, csp,
                                                out_adj, loss_part);
  k_scalars<<<dim3(1), dim3(64), 0, stream>>>(loss_part, out_sc);
}